// Round 5
// baseline (251.936 us; speedup 1.0000x reference)
//
#include <hip/hip_runtime.h>
#include <hip/hip_bf16.h>
#include <math.h>

typedef __attribute__((ext_vector_type(4))) float f32x4;
typedef __attribute__((ext_vector_type(8))) short short8;

#define N_NODES 8192
#define KSEGS 16
#define SEG    (N_NODES / KSEGS)    // 512 cols per block
#define NKB    (SEG / 32)           // 16 k-steps per block
#define LOG2E  1.44269504088896f

// f32 -> bf16 bits, round-to-nearest-even
__device__ __forceinline__ short f2bf(float x) {
    unsigned u = __float_as_uint(x);
    u += 0x7FFFu + ((u >> 16) & 1u);
    return (short)(u >> 16);
}
__device__ __forceinline__ float bf2f(short s) {
    return __uint_as_float(((unsigned)(unsigned short)s) << 16);
}
__device__ __forceinline__ float expneg(float s) {   // exp(-s)
    return __builtin_amdgcn_exp2f(-LOG2E * s);
}

// ---------------------------------------------------------------------------
// P1: h = x @ W1  [8192,500]@[500,64] with W1 staged in LDS.
// Writes fsrc = exp(-h.a_src), edst = exp(-h.a_dst).
// ---------------------------------------------------------------------------
#define P1_CHUNK 100
__global__ __launch_bounds__(256) void p1_kernel(
    const float* __restrict__ x, const float* __restrict__ W1,
    const float* __restrict__ a1, float* __restrict__ h,
    float* __restrict__ fsrc, float* __restrict__ edst)
{
    __shared__ float wtile[P1_CHUNK * 64];
    const int lane = threadIdx.x & 63;
    const int w    = threadIdx.x >> 6;
    const int r0   = blockIdx.x * 32 + w * 8;

    float acc[8];
#pragma unroll
    for (int r = 0; r < 8; ++r) acc[r] = 0.f;

    for (int c = 0; c < 5; ++c) {
        const int kb = c * P1_CHUNK;
        __syncthreads();
        for (int idx = threadIdx.x; idx < P1_CHUNK * 64; idx += 256)
            wtile[idx] = W1[kb * 64 + idx];
        __syncthreads();
        for (int kk = 0; kk < P1_CHUNK; kk += 4) {
            float w0 = wtile[(kk + 0) * 64 + lane];
            float w1 = wtile[(kk + 1) * 64 + lane];
            float w2 = wtile[(kk + 2) * 64 + lane];
            float w3 = wtile[(kk + 3) * 64 + lane];
#pragma unroll
            for (int r = 0; r < 8; ++r) {
                f32x4 xv = *(const f32x4*)(x + (size_t)(r0 + r) * 500 + kb + kk);
                acc[r] = fmaf(xv[0], w0, acc[r]);
                acc[r] = fmaf(xv[1], w1, acc[r]);
                acc[r] = fmaf(xv[2], w2, acc[r]);
                acc[r] = fmaf(xv[3], w3, acc[r]);
            }
        }
    }
    float a_s = a1[lane], a_d = a1[64 + lane];
#pragma unroll
    for (int r = 0; r < 8; ++r) {
        h[(size_t)(r0 + r) * 64 + lane] = acc[r];
        float ps = acc[r] * a_s, pd = acc[r] * a_d;
        for (int off = 32; off > 0; off >>= 1) {
            ps += __shfl_down(ps, off); pd += __shfl_down(pd, off);
        }
        if (lane == 0) {
            fsrc[r0 + r] = expneg(ps);
            edst[r0 + r] = expneg(pd);
        }
    }
}

// ---------------------------------------------------------------------------
// Swizzle f32 matrix into bf16 B-fragment order:
// hB[kb][nb][lane][i] = bf16( h[kb*32 + (lane>>4)*8 + i][nb*16 + (lane&15)] )
// ---------------------------------------------------------------------------
__global__ __launch_bounds__(256) void swizzle_kernel(
    const float* __restrict__ h, short* __restrict__ hB,
    int nblk, int ncols, int total)
{
    int tid = blockIdx.x * 256 + threadIdx.x;
    if (tid >= total) return;
    int i  = tid & 7;
    int l  = (tid >> 3) & 63;
    int t2 = tid >> 9;
    int nb = t2 % nblk;
    int kb = t2 / nblk;
    int row = kb * 32 + (l >> 4) * 8 + i;
    int col = nb * 16 + (l & 15);
    hB[tid] = f2bf(h[(size_t)row * ncols + col]);
}

// ---------------------------------------------------------------------------
// GAT layer 1. Block = 8 waves x 16 rows = 128 rows; k-range = 512 cols
// (seg). B-slice (512x64 bf16 = 64KB, fragment order) + edst slice staged in
// LDS ONCE; k-loop has ONLY per-lane adj loads in the VMEM stream (depth-1
// peeled prefetch) -> vmcnt waits never drain the prefetch. Each wave owns
// its 16 rows: no cross-wave reduction. Also emits adjB = bf16(adj).
// ---------------------------------------------------------------------------
__global__ __launch_bounds__(512, 4) void gat1_kernel(
    const float* __restrict__ adj, const float* __restrict__ fsrc,
    const float* __restrict__ edst, const short* __restrict__ hB,
    short* __restrict__ adjB, float* __restrict__ outp,
    float* __restrict__ normp)
{
    __shared__ __align__(16) short Bs[NKB * 4 * 64 * 8];   // 64 KB
    __shared__ __align__(16) float Es[SEG];                // 2 KB

    const int lane = threadIdx.x & 63;
    const int w    = threadIdx.x >> 6;
    const int seg  = blockIdx.y;
    const int r    = lane & 15;
    const int g    = lane >> 4;
    const int rowbase = blockIdx.x * 128 + w * 16;
    const int my_row  = rowbase + r;

    // stage B-slice (16 kb x 4 nb x 64 lanes x 8) and E-slice
    {
        const short8* src = (const short8*)(hB + (size_t)seg * NKB * 4 * 64 * 8);
        short8* dst = (short8*)Bs;
#pragma unroll
        for (int j = 0; j < 8; ++j)
            dst[threadIdx.x + 512 * j] = src[threadIdx.x + 512 * j];
        Es[threadIdx.x] = edst[seg * SEG + threadIdx.x];
    }
    __syncthreads();

    const float F_i = fsrc[my_row];
    const float* arow = adj + (size_t)my_row * N_NODES + seg * SEG + g * 8;

    f32x4 acc[4];
#pragma unroll
    for (int nb = 0; nb < 4; ++nb) acc[nb] = (f32x4){0.f, 0.f, 0.f, 0.f};
    float nacc = 0.f;

    auto compute = [&](int kb, f32x4 a0, f32x4 a1) {
        f32x4 e0 = *(const f32x4*)&Es[kb * 32 + g * 8];
        f32x4 e1 = *(const f32x4*)&Es[kb * 32 + g * 8 + 4];
        short8 af, ab;
#pragma unroll
        for (int t = 0; t < 4; ++t) {
            float sg  = __builtin_amdgcn_rcpf(fmaf(F_i, e0[t], 1.0f));
            float att = sg * a0[t];
            nacc = fmaf(att, att, nacc);
            af[t] = f2bf(att);
            ab[t] = f2bf(a0[t]);
        }
#pragma unroll
        for (int t = 0; t < 4; ++t) {
            float sg  = __builtin_amdgcn_rcpf(fmaf(F_i, e1[t], 1.0f));
            float att = sg * a1[t];
            nacc = fmaf(att, att, nacc);
            af[4 + t] = f2bf(att);
            ab[4 + t] = f2bf(a1[t]);
        }
        *(short8*)(adjB + (size_t)my_row * N_NODES + seg * SEG + kb * 32 + g * 8) = ab;
#pragma unroll
        for (int nb = 0; nb < 4; ++nb) {
            short8 bf = *(const short8*)&Bs[((kb * 4 + nb) * 64 + lane) * 8];
            acc[nb] = __builtin_amdgcn_mfma_f32_16x16x32_bf16(af, bf, acc[nb], 0, 0, 0);
        }
    };

    f32x4 a0c = *(const f32x4*)(arow);
    f32x4 a1c = *(const f32x4*)(arow + 4);
    for (int kb = 0; kb < NKB - 1; ++kb) {
        f32x4 a0n = *(const f32x4*)(arow + (kb + 1) * 32);
        f32x4 a1n = *(const f32x4*)(arow + (kb + 1) * 32 + 4);
        compute(kb, a0c, a1c);
        a0c = a0n; a1c = a1n;
    }
    compute(NKB - 1, a0c, a1c);

    // per-row norm partial: sum over the 4 g-lanes of each row
    nacc += __shfl_xor(nacc, 16);
    nacc += __shfl_xor(nacc, 32);
    if (lane < 16) normp[(size_t)seg * N_NODES + rowbase + lane] = nacc;

    // C/D layout: col = lane&15, row = g*4 + rr
#pragma unroll
    for (int nb = 0; nb < 4; ++nb)
#pragma unroll
        for (int rr = 0; rr < 4; ++rr)
            outp[((size_t)seg * N_NODES + rowbase + g * 4 + rr) * 64 + nb * 16 + r]
                = acc[nb][rr];
}

// ---------------------------------------------------------------------------
// GAT layer 2: same structure; A = bf16 adjB (L3-resident), B-slice = 16 KB.
// ---------------------------------------------------------------------------
__global__ __launch_bounds__(512, 8) void gat2_kernel(
    const short* __restrict__ adjB, const float* __restrict__ fsrc,
    const float* __restrict__ edst, const short* __restrict__ zB,
    float* __restrict__ outp, float* __restrict__ normp)
{
    __shared__ __align__(16) short Zs[NKB * 64 * 8];   // 16 KB
    __shared__ __align__(16) float Es[SEG];            // 2 KB

    const int lane = threadIdx.x & 63;
    const int w    = threadIdx.x >> 6;
    const int seg  = blockIdx.y;
    const int r    = lane & 15;
    const int g    = lane >> 4;
    const int rowbase = blockIdx.x * 128 + w * 16;
    const int my_row  = rowbase + r;

    {
        const short8* src = (const short8*)(zB + (size_t)seg * NKB * 64 * 8);
        short8* dst = (short8*)Zs;
#pragma unroll
        for (int j = 0; j < 2; ++j)
            dst[threadIdx.x + 512 * j] = src[threadIdx.x + 512 * j];
        Es[threadIdx.x] = edst[seg * SEG + threadIdx.x];
    }
    __syncthreads();

    const float F_i = fsrc[my_row];
    const short* arow = adjB + (size_t)my_row * N_NODES + seg * SEG + g * 8;

    f32x4 acc = (f32x4){0.f, 0.f, 0.f, 0.f};
    float nacc = 0.f;

    auto compute = [&](int kb, short8 av) {
        f32x4 e0 = *(const f32x4*)&Es[kb * 32 + g * 8];
        f32x4 e1 = *(const f32x4*)&Es[kb * 32 + g * 8 + 4];
        short8 af;
#pragma unroll
        for (int t = 0; t < 4; ++t) {
            float a   = bf2f(av[t]);
            float sg  = __builtin_amdgcn_rcpf(fmaf(F_i, e0[t], 1.0f));
            float att = sg * a;
            nacc = fmaf(att, att, nacc);
            af[t] = f2bf(att);
        }
#pragma unroll
        for (int t = 0; t < 4; ++t) {
            float a   = bf2f(av[4 + t]);
            float sg  = __builtin_amdgcn_rcpf(fmaf(F_i, e1[t], 1.0f));
            float att = sg * a;
            nacc = fmaf(att, att, nacc);
            af[4 + t] = f2bf(att);
        }
        short8 bf = *(const short8*)&Zs[(kb * 64 + lane) * 8];
        acc = __builtin_amdgcn_mfma_f32_16x16x32_bf16(af, bf, acc, 0, 0, 0);
    };

    short8 avc = *(const short8*)(arow);
    for (int kb = 0; kb < NKB - 1; ++kb) {
        short8 avn = *(const short8*)(arow + (kb + 1) * 32);
        compute(kb, avc);
        avc = avn;
    }
    compute(NKB - 1, avc);

    nacc += __shfl_xor(nacc, 16);
    nacc += __shfl_xor(nacc, 32);
    if (lane < 16) normp[(size_t)seg * N_NODES + rowbase + lane] = nacc;

#pragma unroll
    for (int rr = 0; rr < 4; ++rr)
        outp[((size_t)seg * N_NODES + rowbase + g * 4 + rr) * 16 + r] = acc[rr];
}

// ---------------------------------------------------------------------------
// R1: h1[i][f] = sum_seg outp1 / (sqrt(sum_seg normp1) + 1e-10)
// ---------------------------------------------------------------------------
__global__ __launch_bounds__(256) void r1_kernel(
    const float* __restrict__ outp, const float* __restrict__ normp,
    float* __restrict__ h1)
{
    int tid = blockIdx.x * 256 + threadIdx.x;
    int i = tid >> 6, f = tid & 63;
    float s = 0.f, n = 0.f;
#pragma unroll
    for (int sg = 0; sg < KSEGS; ++sg) {
        s += outp[((size_t)sg * N_NODES + i) * 64 + f];
        n += normp[sg * N_NODES + i];
    }
    h1[tid] = s / (sqrtf(n) + 1e-10f);
}

// ---------------------------------------------------------------------------
// P2: z = h1 @ W2 (padded to 16 cols), fsrc2/edst2 = exp(-z . a2 halves)
// ---------------------------------------------------------------------------
__global__ __launch_bounds__(256) void p2_kernel(
    const float* __restrict__ h1, const float* __restrict__ W2,
    const float* __restrict__ a2, float* __restrict__ z,
    float* __restrict__ fsrc2, float* __restrict__ edst2)
{
    int i = blockIdx.x * 256 + threadIdx.x;
    if (i >= N_NODES) return;
    float zz[10];
#pragma unroll
    for (int c = 0; c < 10; ++c) zz[c] = 0.f;
    for (int f = 0; f < 64; ++f) {
        float hv = h1[(size_t)i * 64 + f];
#pragma unroll
        for (int c = 0; c < 10; ++c) zz[c] = fmaf(hv, W2[f * 10 + c], zz[c]);
    }
    float s1 = 0.f, s2 = 0.f;
#pragma unroll
    for (int c = 0; c < 10; ++c) {
        s1 = fmaf(zz[c], a2[c], s1);
        s2 = fmaf(zz[c], a2[10 + c], s2);
        z[(size_t)i * 16 + c] = zz[c];
    }
#pragma unroll
    for (int c = 10; c < 16; ++c) z[(size_t)i * 16 + c] = 0.f;
    fsrc2[i] = expneg(s1);
    edst2[i] = expneg(s2);
}

// ---------------------------------------------------------------------------
// R2: h2 = partials/norm, then log_softmax over 10 classes -> d_out
// ---------------------------------------------------------------------------
__global__ __launch_bounds__(256) void r2_kernel(
    const float* __restrict__ outp, const float* __restrict__ normp,
    float* __restrict__ out)
{
    int i = blockIdx.x * 256 + threadIdx.x;
    if (i >= N_NODES) return;
    float n = 0.f;
#pragma unroll
    for (int sg = 0; sg < KSEGS; ++sg) n += normp[sg * N_NODES + i];
    float inv = 1.0f / (sqrtf(n) + 1e-10f);
    float v[10];
    float m = -1e30f;
#pragma unroll
    for (int c = 0; c < 10; ++c) {
        float s = 0.f;
#pragma unroll
        for (int sg = 0; sg < KSEGS; ++sg)
            s += outp[((size_t)sg * N_NODES + i) * 16 + c];
        v[c] = s * inv;
        m = fmaxf(m, v[c]);
    }
    float es = 0.f;
#pragma unroll
    for (int c = 0; c < 10; ++c) es += expf(v[c] - m);
    float lse = m + logf(es);
#pragma unroll
    for (int c = 0; c < 10; ++c) out[(size_t)i * 10 + c] = v[c] - lse;
}

extern "C" void kernel_launch(void* const* d_in, const int* in_sizes, int n_in,
                              void* d_out, int out_size, void* d_ws, size_t ws_size,
                              hipStream_t stream)
{
    const float* x   = (const float*)d_in[0];
    const float* adj = (const float*)d_in[1];
    const float* W1  = (const float*)d_in[2];
    const float* a1  = (const float*)d_in[3];
    const float* W2  = (const float*)d_in[4];
    const float* a2  = (const float*)d_in[5];
    float* out = (float*)d_out;

    char* ws = (char*)d_ws;
    size_t off = 0;
    auto alloc = [&](size_t bytes) -> void* {
        void* p = ws + off;
        off += (bytes + 255) & ~(size_t)255;
        return p;
    };
    short* adjB   = (short*)alloc((size_t)N_NODES * N_NODES * 2);   // 134MB
    float* h      = (float*)alloc((size_t)N_NODES * 64 * 4);
    float* fsrc1  = (float*)alloc((size_t)N_NODES * 4);
    float* edst1  = (float*)alloc((size_t)N_NODES * 4);
    short* hB1    = (short*)alloc((size_t)N_NODES * 64 * 2);
    float* outp1  = (float*)alloc((size_t)KSEGS * N_NODES * 64 * 4);  // 33.5MB
    float* normp1 = (float*)alloc((size_t)KSEGS * N_NODES * 4);
    float* h1     = (float*)alloc((size_t)N_NODES * 64 * 4);
    float* z      = (float*)alloc((size_t)N_NODES * 16 * 4);
    float* fsrc2  = (float*)alloc((size_t)N_NODES * 4);
    float* edst2  = (float*)alloc((size_t)N_NODES * 4);
    short* zB     = (short*)alloc((size_t)N_NODES * 16 * 2);
    float* outp2  = (float*)alloc((size_t)KSEGS * N_NODES * 16 * 4);
    float* normp2 = (float*)alloc((size_t)KSEGS * N_NODES * 4);

    hipLaunchKernelGGL(p1_kernel, dim3(N_NODES / 32), dim3(256), 0, stream,
                       x, W1, a1, h, fsrc1, edst1);
    hipLaunchKernelGGL(swizzle_kernel, dim3(2048), dim3(256), 0, stream,
                       h, hB1, 4, 64, N_NODES * 64);
    hipLaunchKernelGGL(gat1_kernel, dim3(N_NODES / 128, KSEGS), dim3(512), 0, stream,
                       adj, fsrc1, edst1, hB1, adjB, outp1, normp1);
    hipLaunchKernelGGL(r1_kernel, dim3(2048), dim3(256), 0, stream,
                       outp1, normp1, h1);
    hipLaunchKernelGGL(p2_kernel, dim3(32), dim3(256), 0, stream,
                       h1, W2, a2, z, fsrc2, edst2);
    hipLaunchKernelGGL(swizzle_kernel, dim3(512), dim3(256), 0, stream,
                       z, zB, 1, 16, N_NODES * 16);
    hipLaunchKernelGGL(gat2_kernel, dim3(N_NODES / 128, KSEGS), dim3(512), 0, stream,
                       adjB, fsrc2, edst2, zB, outp2, normp2);
    hipLaunchKernelGGL(r2_kernel, dim3(32), dim3(256), 0, stream,
                       outp2, normp2, out);
}